// Round 1
// baseline (607.157 us; speedup 1.0000x reference)
//
#include <hip/hip_runtime.h>
#include <hip/hip_bf16.h>
#include <math.h>

#define DIMF 256   // feature dim (d = h = 256)
#define OUTC 2     // output classes

// ---------------------------------------------------------------------------
// CSR build kernels
// ---------------------------------------------------------------------------
__global__ __launch_bounds__(256) void hist_kernel(const int* __restrict__ dst,
                                                   int* __restrict__ indeg, int E) {
    int e = blockIdx.x * 256 + threadIdx.x;
    if (e < E) atomicAdd(&indeg[dst[e]], 1);
}

__global__ __launch_bounds__(256) void dinv_kernel(const int* __restrict__ indeg,
                                                   float* __restrict__ dinv, int N) {
    int i = blockIdx.x * 256 + threadIdx.x;
    if (i < N) dinv[i] = rsqrtf((float)(indeg[i] + 1));  // +1 self-loop
}

__global__ __launch_bounds__(1024) void scan_kernel(const int* __restrict__ indeg,
                                                    int* __restrict__ rowptr, int n) {
    __shared__ int sm[1024];
    int tid = threadIdx.x;
    int carry = 0;
    for (int base = 0; base < n; base += 1024) {
        int i = base + tid;
        int v = (i < n) ? indeg[i] : 0;
        sm[tid] = v;
        __syncthreads();
        int x = v;
        for (int off = 1; off < 1024; off <<= 1) {
            int t = (tid >= off) ? sm[tid - off] : 0;
            __syncthreads();
            x += t;
            sm[tid] = x;
            __syncthreads();
        }
        if (i < n) rowptr[i] = carry + x - v;  // exclusive scan
        carry += sm[1023];
        __syncthreads();
    }
    if (tid == 0) rowptr[n] = carry;
}

__global__ __launch_bounds__(256) void copy_kernel(const int* __restrict__ src,
                                                   int* __restrict__ dst, int n) {
    int i = blockIdx.x * 256 + threadIdx.x;
    if (i < n) dst[i] = src[i];
}

__global__ __launch_bounds__(256) void scatter_kernel(const int* __restrict__ esrc,
                                                      const int* __restrict__ edst,
                                                      int* __restrict__ cursor,
                                                      int* __restrict__ col, int E) {
    int e = blockIdx.x * 256 + threadIdx.x;
    if (e < E) {
        int d = edst[e];
        int pos = atomicAdd(&cursor[d], 1);
        col[pos] = esrc[e];
    }
}

// ---------------------------------------------------------------------------
// fp32 register-tiled GEMM: C[M x 256] = A[M x 256] * B[256 x 256]
// BM=BN=64, BK=16, 256 threads, 4x4 micro-tile per thread
// ---------------------------------------------------------------------------
#define BM 64
#define BN 64
#define BK 16

__global__ __launch_bounds__(256) void gemm_fp32(const float* __restrict__ A,
                                                 const float* __restrict__ B,
                                                 float* __restrict__ C, int M) {
    __shared__ float As[BK][BM + 4];  // +4 keeps 16B alignment, breaks bank stride
    __shared__ float Bs[BK][BN];

    const int Kdim = DIMF, Ndim = DIMF;
    int tid = threadIdx.x;
    int row0 = blockIdx.x * BM;
    int col0 = blockIdx.y * BN;
    int tx = tid & 15;  // n-dir
    int ty = tid >> 4;  // m-dir

    // loader indices
    int la_m = tid >> 2;         // 0..63
    int la_k = (tid & 3) * 4;    // 0,4,8,12
    int lb_k = tid >> 4;         // 0..15
    int lb_n = (tid & 15) * 4;   // 0..60

    float acc[4][4] = {};

    for (int k0 = 0; k0 < Kdim; k0 += BK) {
        float4 av = make_float4(0.f, 0.f, 0.f, 0.f);
        int ar = row0 + la_m;
        if (ar < M) av = *(const float4*)&A[(size_t)ar * Kdim + k0 + la_k];
        float4 bv = *(const float4*)&B[(size_t)(k0 + lb_k) * Ndim + col0 + lb_n];
        __syncthreads();
        As[la_k + 0][la_m] = av.x;
        As[la_k + 1][la_m] = av.y;
        As[la_k + 2][la_m] = av.z;
        As[la_k + 3][la_m] = av.w;
        *(float4*)&Bs[lb_k][lb_n] = bv;
        __syncthreads();
#pragma unroll
        for (int k = 0; k < BK; ++k) {
            float4 a = *(const float4*)&As[k][ty * 4];
            float4 b = *(const float4*)&Bs[k][tx * 4];
            acc[0][0] = fmaf(a.x, b.x, acc[0][0]);
            acc[0][1] = fmaf(a.x, b.y, acc[0][1]);
            acc[0][2] = fmaf(a.x, b.z, acc[0][2]);
            acc[0][3] = fmaf(a.x, b.w, acc[0][3]);
            acc[1][0] = fmaf(a.y, b.x, acc[1][0]);
            acc[1][1] = fmaf(a.y, b.y, acc[1][1]);
            acc[1][2] = fmaf(a.y, b.z, acc[1][2]);
            acc[1][3] = fmaf(a.y, b.w, acc[1][3]);
            acc[2][0] = fmaf(a.z, b.x, acc[2][0]);
            acc[2][1] = fmaf(a.z, b.y, acc[2][1]);
            acc[2][2] = fmaf(a.z, b.z, acc[2][2]);
            acc[2][3] = fmaf(a.z, b.w, acc[2][3]);
            acc[3][0] = fmaf(a.w, b.x, acc[3][0]);
            acc[3][1] = fmaf(a.w, b.y, acc[3][1]);
            acc[3][2] = fmaf(a.w, b.z, acc[3][2]);
            acc[3][3] = fmaf(a.w, b.w, acc[3][3]);
        }
    }

#pragma unroll
    for (int i = 0; i < 4; ++i) {
        int row = row0 + ty * 4 + i;
        if (row < M) {
            float4 v = make_float4(acc[i][0], acc[i][1], acc[i][2], acc[i][3]);
            *(float4*)&C[(size_t)row * Ndim + col0 + tx * 4] = v;
        }
    }
}

// ---------------------------------------------------------------------------
// Aggregation: out[i] = relu( dinv[i]^2*H[i] + sum_{e in CSR(i)} dinv[s]*dinv[i]*H[s] + b )
// one wave per node; lane handles 4 features (float4)
// ---------------------------------------------------------------------------
__global__ __launch_bounds__(256) void agg_kernel(const float* __restrict__ H,
                                                  const int* __restrict__ rowptr,
                                                  const int* __restrict__ col,
                                                  const float* __restrict__ dinv,
                                                  const float* __restrict__ bias,
                                                  float* __restrict__ out, int N) {
    int wave = threadIdx.x >> 6;
    int lane = threadIdx.x & 63;
    int node = blockIdx.x * 4 + wave;
    if (node >= N) return;

    float di = dinv[node];
    float4 acc;
    {
        float4 h = *(const float4*)&H[(size_t)node * DIMF + lane * 4];
        float w = di * di;
        acc.x = h.x * w; acc.y = h.y * w; acc.z = h.z * w; acc.w = h.w * w;
    }
    int e0 = rowptr[node], e1 = rowptr[node + 1];
    for (int e = e0; e < e1; ++e) {
        int s = col[e];
        float w = dinv[s] * di;
        float4 h = *(const float4*)&H[(size_t)s * DIMF + lane * 4];
        acc.x = fmaf(h.x, w, acc.x);
        acc.y = fmaf(h.y, w, acc.y);
        acc.z = fmaf(h.z, w, acc.z);
        acc.w = fmaf(h.w, w, acc.w);
    }
    float4 b = *(const float4*)&bias[lane * 4];
    acc.x += b.x; acc.y += b.y; acc.z += b.z; acc.w += b.w;
    acc.x = fmaxf(acc.x, 0.f); acc.y = fmaxf(acc.y, 0.f);
    acc.z = fmaxf(acc.z, 0.f); acc.w = fmaxf(acc.w, 0.f);
    *(float4*)&out[(size_t)node * DIMF + lane * 4] = acc;
}

// ---------------------------------------------------------------------------
// Final FC (256 -> 2) + log_softmax; one wave per node
// ---------------------------------------------------------------------------
__global__ __launch_bounds__(256) void fc_lsm_kernel(const float* __restrict__ H,
                                                     const float* __restrict__ Wfc,
                                                     const float* __restrict__ bfc,
                                                     float* __restrict__ out, int N) {
    int wave = threadIdx.x >> 6;
    int lane = threadIdx.x & 63;
    int node = blockIdx.x * 4 + wave;
    if (node >= N) return;

    float4 h = *(const float4*)&H[(size_t)node * DIMF + lane * 4];
    float4 w0 = *(const float4*)&Wfc[lane * 8];      // [k0][0],[k0][1],[k1][0],[k1][1]
    float4 w1 = *(const float4*)&Wfc[lane * 8 + 4];  // [k2][0],[k2][1],[k3][0],[k3][1]
    float s0 = h.x * w0.x + h.y * w0.z + h.z * w1.x + h.w * w1.z;
    float s1 = h.x * w0.y + h.y * w0.w + h.z * w1.y + h.w * w1.w;
#pragma unroll
    for (int off = 32; off > 0; off >>= 1) {
        s0 += __shfl_xor(s0, off);
        s1 += __shfl_xor(s1, off);
    }
    if (lane == 0) {
        s0 += bfc[0];
        s1 += bfc[1];
        float m = fmaxf(s0, s1);
        float lse = m + logf(__expf(s0 - m) + __expf(s1 - m));
        out[(size_t)node * 2 + 0] = s0 - lse;
        out[(size_t)node * 2 + 1] = s1 - lse;
    }
}

// ---------------------------------------------------------------------------
// Host launcher
// ---------------------------------------------------------------------------
static inline size_t align256(size_t x) { return (x + 255) & ~(size_t)255; }

extern "C" void kernel_launch(void* const* d_in, const int* in_sizes, int n_in,
                              void* d_out, int out_size, void* d_ws, size_t ws_size,
                              hipStream_t stream) {
    const float* x   = (const float*)d_in[0];
    const int* eidx  = (const int*)d_in[1];
    const float* W1  = (const float*)d_in[2];
    const float* b1  = (const float*)d_in[3];
    const float* W2  = (const float*)d_in[4];
    const float* b2  = (const float*)d_in[5];
    const float* Wfc = (const float*)d_in[6];
    const float* bfc = (const float*)d_in[7];
    float* out = (float*)d_out;

    const int N = in_sizes[0] / DIMF;     // 50000
    const int E = in_sizes[1] / 2;        // 800000
    const int* esrc = eidx;
    const int* edst = eidx + E;

    // workspace layout
    char* w = (char*)d_ws;
    size_t off = 0;
    int*   indeg  = (int*)(w + off);   off = align256(off + (size_t)N * 4);
    float* dinv   = (float*)(w + off); off = align256(off + (size_t)N * 4);
    int*   rowptr = (int*)(w + off);   off = align256(off + (size_t)(N + 1) * 4);
    int*   cursor = (int*)(w + off);   off = align256(off + (size_t)N * 4);
    int*   col    = (int*)(w + off);   off = align256(off + (size_t)E * 4);
    float* bufA   = (float*)(w + off); off = align256(off + (size_t)N * DIMF * 4);
    float* bufB   = (float*)(w + off); off = align256(off + (size_t)N * DIMF * 4);
    (void)ws_size;

    int gE = (E + 255) / 256;
    int gN = (N + 255) / 256;
    int gNode = (N + 3) / 4;

    // 1) CSR build
    hipMemsetAsync(indeg, 0, (size_t)N * 4, stream);
    hist_kernel<<<gE, 256, 0, stream>>>(edst, indeg, E);
    dinv_kernel<<<gN, 256, 0, stream>>>(indeg, dinv, N);
    scan_kernel<<<1, 1024, 0, stream>>>(indeg, rowptr, N);
    copy_kernel<<<gN, 256, 0, stream>>>(rowptr, cursor, N);
    scatter_kernel<<<gE, 256, 0, stream>>>(esrc, edst, cursor, col, E);

    // 2) conv1: bufA = x @ W1 ; bufB = relu(agg(bufA) + b1)
    dim3 ggrid((N + BM - 1) / BM, DIMF / BN);
    gemm_fp32<<<ggrid, 256, 0, stream>>>(x, W1, bufA, N);
    agg_kernel<<<gNode, 256, 0, stream>>>(bufA, rowptr, col, dinv, b1, bufB, N);

    // 3) conv2: bufA = bufB @ W2 ; bufB = relu(agg(bufA) + b2)
    gemm_fp32<<<ggrid, 256, 0, stream>>>(bufB, W2, bufA, N);
    agg_kernel<<<gNode, 256, 0, stream>>>(bufA, rowptr, col, dinv, b2, bufB, N);

    // 4) FC + log_softmax
    fc_lsm_kernel<<<gNode, 256, 0, stream>>>(bufB, Wfc, bfc, out, N);
}

// Round 2
// 420.986 us; speedup vs baseline: 1.4422x; 1.4422x over previous
//
#include <hip/hip_runtime.h>
#include <hip/hip_bf16.h>
#include <math.h>

#define DIMF 256   // feature dim (d = h = 256)

typedef __attribute__((ext_vector_type(8))) short s16x8;
typedef __attribute__((ext_vector_type(4))) float f32x4;
typedef __attribute__((ext_vector_type(4))) unsigned short u16x4;
typedef __attribute__((ext_vector_type(8))) unsigned short u16x8;

// ---------------------------------------------------------------------------
// CSR build
// ---------------------------------------------------------------------------
__global__ __launch_bounds__(256) void hist_kernel(const int* __restrict__ dst,
                                                   int* __restrict__ indeg, int E) {
    int e = blockIdx.x * 256 + threadIdx.x;
    if (e < E) atomicAdd(&indeg[dst[e]], 1);
}

__global__ __launch_bounds__(256) void dinv_kernel(const int* __restrict__ indeg,
                                                   float* __restrict__ dinv, int N) {
    int i = blockIdx.x * 256 + threadIdx.x;
    if (i < N) dinv[i] = rsqrtf((float)(indeg[i] + 1));  // +1 self-loop
}

// 3-phase exclusive scan of indeg -> rowptr (and cursor copy), 1024 items/block
__global__ __launch_bounds__(256) void scan_partial(const int* __restrict__ indeg,
                                                    int* __restrict__ blockSums, int n) {
    int t = threadIdx.x;
    int base = blockIdx.x * 1024 + t * 4;
    int s = 0;
#pragma unroll
    for (int j = 0; j < 4; ++j) { int i = base + j; if (i < n) s += indeg[i]; }
#pragma unroll
    for (int off = 32; off > 0; off >>= 1) s += __shfl_down(s, off);
    __shared__ int sm[4];
    if ((t & 63) == 0) sm[t >> 6] = s;
    __syncthreads();
    if (t == 0) blockSums[blockIdx.x] = sm[0] + sm[1] + sm[2] + sm[3];
}

__global__ __launch_bounds__(64) void scan_sums(int* __restrict__ blockSums, int nb) {
    int t = threadIdx.x;
    int carry = 0;
    for (int base = 0; base < nb; base += 64) {
        int i = base + t;
        int v = (i < nb) ? blockSums[i] : 0;
        int x = v;
#pragma unroll
        for (int off = 1; off < 64; off <<= 1) {
            int y = __shfl_up(x, off);
            if (t >= off) x += y;
        }
        if (i < nb) blockSums[i] = carry + x - v;  // exclusive
        carry += __shfl(x, 63);
    }
}

__global__ __launch_bounds__(256) void scan_final(const int* __restrict__ indeg,
                                                  const int* __restrict__ blockOffs,
                                                  int* __restrict__ rowptr,
                                                  int* __restrict__ cursor, int n) {
    __shared__ int waveSums[4];
    int t = threadIdx.x;
    int wv = t >> 6, ln = t & 63;
    int base = blockIdx.x * 1024 + t * 4;
    int v[4]; int s = 0;
#pragma unroll
    for (int j = 0; j < 4; ++j) { int i = base + j; v[j] = (i < n) ? indeg[i] : 0; s += v[j]; }
    int x = s;
#pragma unroll
    for (int off = 1; off < 64; off <<= 1) {
        int y = __shfl_up(x, off);
        if (ln >= off) x += y;
    }
    if (ln == 63) waveSums[wv] = x;
    __syncthreads();
    int woff = 0;
    for (int w = 0; w < wv; ++w) woff += waveSums[w];
    int pre = blockOffs[blockIdx.x] + woff + x - s;
#pragma unroll
    for (int j = 0; j < 4; ++j) {
        int i = base + j;
        if (i < n) { rowptr[i] = pre; cursor[i] = pre; }
        pre += v[j];
        if (i == n - 1) rowptr[n] = pre;
    }
}

__global__ __launch_bounds__(256) void scatter_kernel(const int* __restrict__ esrc,
                                                      const int* __restrict__ edst,
                                                      int* __restrict__ cursor,
                                                      int* __restrict__ col, int E) {
    int e = blockIdx.x * 256 + threadIdx.x;
    if (e < E) {
        int d = edst[e];
        int pos = atomicAdd(&cursor[d], 1);
        col[pos] = esrc[e];
    }
}

// ---------------------------------------------------------------------------
// MFMA GEMM with bf16 hi/lo split (fp32-accurate): C[Mx256] = A[Mx256]*B[256x256]
// BM=128, BN=64, BK=32; 256 threads = 4 waves (2x2); wave tile 64x32
// ---------------------------------------------------------------------------
#define GBM 128
#define GBN 64
#define GBK 32
#define APAD 40  // LDS row stride in bf16 elems (80 B: breaks bank alignment)

__device__ __forceinline__ void split1(float f, unsigned short& h, unsigned short& l) {
    unsigned u = __float_as_uint(f);
    h = (unsigned short)(u >> 16);
    float r = f - __uint_as_float(u & 0xFFFF0000u);
    l = (unsigned short)(__float_as_uint(r) >> 16);
}

__global__ __launch_bounds__(256) void gemm_mfma(const float* __restrict__ A,
                                                 const float* __restrict__ B,
                                                 float* __restrict__ C, int M) {
    __shared__ unsigned short Ah[GBM * APAD];
    __shared__ unsigned short Al[GBM * APAD];
    __shared__ unsigned short Bh[GBN * APAD];
    __shared__ unsigned short Bl[GBN * APAD];

    const int t = threadIdx.x;
    const int row0 = blockIdx.x * GBM;
    const int col0 = blockIdx.y * GBN;

    // A stage indices: thread -> (row r, k-half kh)
    const int sa_r = t >> 1;
    const int sa_kh = (t & 1) * 16;
    const bool sa_valid = (row0 + sa_r) < M;
    // B stage indices: thread -> (col c, k-quarter kq)
    const int sb_c = t & 63;
    const int sb_kq = t >> 6;

    // wave/fragment indices
    const int wv = t >> 6;
    const int wm = wv >> 1;       // 0..1
    const int wn = wv & 1;        // 0..1
    const int ln = t & 63;
    const int lr = ln & 15;
    const int lk = (ln >> 4) * 8;

    f32x4 acc[4][2] = {};

    for (int k0 = 0; k0 < DIMF; k0 += GBK) {
        // --- load to regs ---
        float4 av[4];
        const float* ap = A + (size_t)(row0 + sa_r) * DIMF + k0 + sa_kh;
#pragma unroll
        for (int i = 0; i < 4; ++i)
            av[i] = sa_valid ? *(const float4*)(ap + 4 * i)
                             : make_float4(0.f, 0.f, 0.f, 0.f);
        float bvv[8];
        const float* bp = B + (size_t)(k0 + sb_kq * 8) * DIMF + col0 + sb_c;
#pragma unroll
        for (int j = 0; j < 8; ++j) bvv[j] = bp[(size_t)j * DIMF];

        __syncthreads();  // previous iter's frag reads done

        // --- convert + LDS write ---
#pragma unroll
        for (int i = 0; i < 4; ++i) {
            float f[4] = {av[i].x, av[i].y, av[i].z, av[i].w};
            u16x4 h, l;
#pragma unroll
            for (int q = 0; q < 4; ++q) { unsigned short hh, ll; split1(f[q], hh, ll); h[q] = hh; l[q] = ll; }
            *(u16x4*)&Ah[sa_r * APAD + sa_kh + 4 * i] = h;
            *(u16x4*)&Al[sa_r * APAD + sa_kh + 4 * i] = l;
        }
        {
            u16x8 h, l;
#pragma unroll
            for (int j = 0; j < 8; ++j) { unsigned short hh, ll; split1(bvv[j], hh, ll); h[j] = hh; l[j] = ll; }
            *(u16x8*)&Bh[sb_c * APAD + sb_kq * 8] = h;
            *(u16x8*)&Bl[sb_c * APAD + sb_kq * 8] = l;
        }
        __syncthreads();

        // --- fragments + MFMA ---
        s16x8 ah[4], al[4], bh[2], bl[2];
#pragma unroll
        for (int fm = 0; fm < 4; ++fm) {
            int r = wm * 64 + fm * 16 + lr;
            ah[fm] = *(const s16x8*)&Ah[r * APAD + lk];
            al[fm] = *(const s16x8*)&Al[r * APAD + lk];
        }
#pragma unroll
        for (int fn = 0; fn < 2; ++fn) {
            int c = wn * 32 + fn * 16 + lr;
            bh[fn] = *(const s16x8*)&Bh[c * APAD + lk];
            bl[fn] = *(const s16x8*)&Bl[c * APAD + lk];
        }
#pragma unroll
        for (int fm = 0; fm < 4; ++fm)
#pragma unroll
            for (int fn = 0; fn < 2; ++fn) {
                acc[fm][fn] = __builtin_amdgcn_mfma_f32_16x16x32_bf16(ah[fm], bh[fn], acc[fm][fn], 0, 0, 0);
                acc[fm][fn] = __builtin_amdgcn_mfma_f32_16x16x32_bf16(al[fm], bh[fn], acc[fm][fn], 0, 0, 0);
                acc[fm][fn] = __builtin_amdgcn_mfma_f32_16x16x32_bf16(ah[fm], bl[fn], acc[fm][fn], 0, 0, 0);
            }
    }

    // --- epilogue: C/D layout col=lane&15, row=(lane>>4)*4+reg ---
#pragma unroll
    for (int fm = 0; fm < 4; ++fm)
#pragma unroll
        for (int fn = 0; fn < 2; ++fn)
#pragma unroll
            for (int r = 0; r < 4; ++r) {
                int row = row0 + wm * 64 + fm * 16 + (ln >> 4) * 4 + r;
                int colc = col0 + wn * 32 + fn * 16 + lr;
                if (row < M) C[(size_t)row * DIMF + colc] = acc[fm][fn][r];
            }
}

// ---------------------------------------------------------------------------
// Aggregation (unroll x4): out[i] = relu(dinv[i]^2*H[i] + sum dinv[s]*dinv[i]*H[s] + b)
// one wave per node; lane = 4 features (float4)
// ---------------------------------------------------------------------------
__global__ __launch_bounds__(256) void agg_kernel(const float* __restrict__ H,
                                                  const int* __restrict__ rowptr,
                                                  const int* __restrict__ col,
                                                  const float* __restrict__ dinv,
                                                  const float* __restrict__ bias,
                                                  float* __restrict__ out, int N) {
    int wave = threadIdx.x >> 6;
    int lane = threadIdx.x & 63;
    int node = blockIdx.x * 4 + wave;
    if (node >= N) return;

    float di = dinv[node];
    float4 acc;
    {
        float4 h = *(const float4*)&H[(size_t)node * DIMF + lane * 4];
        float w = di * di;
        acc.x = h.x * w; acc.y = h.y * w; acc.z = h.z * w; acc.w = h.w * w;
    }
    int e0 = rowptr[node], e1 = rowptr[node + 1];
    int e = e0;
    for (; e + 4 <= e1; e += 4) {
        int s0 = col[e + 0], s1 = col[e + 1], s2 = col[e + 2], s3 = col[e + 3];
        float w0 = dinv[s0] * di, w1 = dinv[s1] * di, w2 = dinv[s2] * di, w3 = dinv[s3] * di;
        float4 h0 = *(const float4*)&H[(size_t)s0 * DIMF + lane * 4];
        float4 h1 = *(const float4*)&H[(size_t)s1 * DIMF + lane * 4];
        float4 h2 = *(const float4*)&H[(size_t)s2 * DIMF + lane * 4];
        float4 h3 = *(const float4*)&H[(size_t)s3 * DIMF + lane * 4];
        acc.x = fmaf(h0.x, w0, acc.x); acc.y = fmaf(h0.y, w0, acc.y);
        acc.z = fmaf(h0.z, w0, acc.z); acc.w = fmaf(h0.w, w0, acc.w);
        acc.x = fmaf(h1.x, w1, acc.x); acc.y = fmaf(h1.y, w1, acc.y);
        acc.z = fmaf(h1.z, w1, acc.z); acc.w = fmaf(h1.w, w1, acc.w);
        acc.x = fmaf(h2.x, w2, acc.x); acc.y = fmaf(h2.y, w2, acc.y);
        acc.z = fmaf(h2.z, w2, acc.z); acc.w = fmaf(h2.w, w2, acc.w);
        acc.x = fmaf(h3.x, w3, acc.x); acc.y = fmaf(h3.y, w3, acc.y);
        acc.z = fmaf(h3.z, w3, acc.z); acc.w = fmaf(h3.w, w3, acc.w);
    }
    for (; e < e1; ++e) {
        int s = col[e];
        float w = dinv[s] * di;
        float4 h = *(const float4*)&H[(size_t)s * DIMF + lane * 4];
        acc.x = fmaf(h.x, w, acc.x); acc.y = fmaf(h.y, w, acc.y);
        acc.z = fmaf(h.z, w, acc.z); acc.w = fmaf(h.w, w, acc.w);
    }
    float4 b = *(const float4*)&bias[lane * 4];
    acc.x = fmaxf(acc.x + b.x, 0.f); acc.y = fmaxf(acc.y + b.y, 0.f);
    acc.z = fmaxf(acc.z + b.z, 0.f); acc.w = fmaxf(acc.w + b.w, 0.f);
    *(float4*)&out[(size_t)node * DIMF + lane * 4] = acc;
}

// ---------------------------------------------------------------------------
// Fused: agg2 + bias + relu + FC(256->2) + log_softmax (no 51MB round-trip)
// ---------------------------------------------------------------------------
__global__ __launch_bounds__(256) void agg_fc_kernel(const float* __restrict__ H,
                                                     const int* __restrict__ rowptr,
                                                     const int* __restrict__ col,
                                                     const float* __restrict__ dinv,
                                                     const float* __restrict__ bias,
                                                     const float* __restrict__ Wfc,
                                                     const float* __restrict__ bfc,
                                                     float* __restrict__ out, int N) {
    int wave = threadIdx.x >> 6;
    int lane = threadIdx.x & 63;
    int node = blockIdx.x * 4 + wave;
    if (node >= N) return;

    float di = dinv[node];
    float4 acc;
    {
        float4 h = *(const float4*)&H[(size_t)node * DIMF + lane * 4];
        float w = di * di;
        acc.x = h.x * w; acc.y = h.y * w; acc.z = h.z * w; acc.w = h.w * w;
    }
    int e0 = rowptr[node], e1 = rowptr[node + 1];
    int e = e0;
    for (; e + 4 <= e1; e += 4) {
        int s0 = col[e + 0], s1 = col[e + 1], s2 = col[e + 2], s3 = col[e + 3];
        float w0 = dinv[s0] * di, w1 = dinv[s1] * di, w2 = dinv[s2] * di, w3 = dinv[s3] * di;
        float4 h0 = *(const float4*)&H[(size_t)s0 * DIMF + lane * 4];
        float4 h1 = *(const float4*)&H[(size_t)s1 * DIMF + lane * 4];
        float4 h2 = *(const float4*)&H[(size_t)s2 * DIMF + lane * 4];
        float4 h3 = *(const float4*)&H[(size_t)s3 * DIMF + lane * 4];
        acc.x = fmaf(h0.x, w0, acc.x); acc.y = fmaf(h0.y, w0, acc.y);
        acc.z = fmaf(h0.z, w0, acc.z); acc.w = fmaf(h0.w, w0, acc.w);
        acc.x = fmaf(h1.x, w1, acc.x); acc.y = fmaf(h1.y, w1, acc.y);
        acc.z = fmaf(h1.z, w1, acc.z); acc.w = fmaf(h1.w, w1, acc.w);
        acc.x = fmaf(h2.x, w2, acc.x); acc.y = fmaf(h2.y, w2, acc.y);
        acc.z = fmaf(h2.z, w2, acc.z); acc.w = fmaf(h2.w, w2, acc.w);
        acc.x = fmaf(h3.x, w3, acc.x); acc.y = fmaf(h3.y, w3, acc.y);
        acc.z = fmaf(h3.z, w3, acc.z); acc.w = fmaf(h3.w, w3, acc.w);
    }
    for (; e < e1; ++e) {
        int s = col[e];
        float w = dinv[s] * di;
        float4 h = *(const float4*)&H[(size_t)s * DIMF + lane * 4];
        acc.x = fmaf(h.x, w, acc.x); acc.y = fmaf(h.y, w, acc.y);
        acc.z = fmaf(h.z, w, acc.z); acc.w = fmaf(h.w, w, acc.w);
    }
    float4 b = *(const float4*)&bias[lane * 4];
    acc.x = fmaxf(acc.x + b.x, 0.f); acc.y = fmaxf(acc.y + b.y, 0.f);
    acc.z = fmaxf(acc.z + b.z, 0.f); acc.w = fmaxf(acc.w + b.w, 0.f);

    // FC: Wfc is [256][2] row-major; lane covers k = lane*4..lane*4+3
    float4 w0 = *(const float4*)&Wfc[lane * 8];
    float4 w1 = *(const float4*)&Wfc[lane * 8 + 4];
    float s0 = acc.x * w0.x + acc.y * w0.z + acc.z * w1.x + acc.w * w1.z;
    float s1 = acc.x * w0.y + acc.y * w0.w + acc.z * w1.y + acc.w * w1.w;
#pragma unroll
    for (int off = 32; off > 0; off >>= 1) {
        s0 += __shfl_xor(s0, off);
        s1 += __shfl_xor(s1, off);
    }
    if (lane == 0) {
        s0 += bfc[0];
        s1 += bfc[1];
        float m = fmaxf(s0, s1);
        float lse = m + logf(__expf(s0 - m) + __expf(s1 - m));
        out[(size_t)node * 2 + 0] = s0 - lse;
        out[(size_t)node * 2 + 1] = s1 - lse;
    }
}

// ---------------------------------------------------------------------------
// Host launcher
// ---------------------------------------------------------------------------
static inline size_t align256(size_t x) { return (x + 255) & ~(size_t)255; }

extern "C" void kernel_launch(void* const* d_in, const int* in_sizes, int n_in,
                              void* d_out, int out_size, void* d_ws, size_t ws_size,
                              hipStream_t stream) {
    const float* x   = (const float*)d_in[0];
    const int* eidx  = (const int*)d_in[1];
    const float* W1  = (const float*)d_in[2];
    const float* b1  = (const float*)d_in[3];
    const float* W2  = (const float*)d_in[4];
    const float* b2  = (const float*)d_in[5];
    const float* Wfc = (const float*)d_in[6];
    const float* bfc = (const float*)d_in[7];
    float* out = (float*)d_out;

    const int N = in_sizes[0] / DIMF;     // 50000
    const int E = in_sizes[1] / 2;        // 800000
    const int* esrc = eidx;
    const int* edst = eidx + E;

    // workspace layout
    char* w = (char*)d_ws;
    size_t off = 0;
    int*   indeg  = (int*)(w + off);   off = align256(off + (size_t)N * 4);
    float* dinv   = (float*)(w + off); off = align256(off + (size_t)N * 4);
    int*   rowptr = (int*)(w + off);   off = align256(off + (size_t)(N + 1) * 4);
    int*   cursor = (int*)(w + off);   off = align256(off + (size_t)N * 4);
    int*   bsums  = (int*)(w + off);   off = align256(off + (size_t)1024 * 4);
    int*   col    = (int*)(w + off);   off = align256(off + (size_t)E * 4);
    float* bufA   = (float*)(w + off); off = align256(off + (size_t)N * DIMF * 4);
    float* bufB   = (float*)(w + off); off = align256(off + (size_t)N * DIMF * 4);
    (void)ws_size;

    int gE = (E + 255) / 256;
    int gN = (N + 255) / 256;
    int gNode = (N + 3) / 4;
    int nb1024 = (N + 1023) / 1024;

    // 1) CSR build
    hipMemsetAsync(indeg, 0, (size_t)N * 4, stream);
    hist_kernel<<<gE, 256, 0, stream>>>(edst, indeg, E);
    dinv_kernel<<<gN, 256, 0, stream>>>(indeg, dinv, N);
    scan_partial<<<nb1024, 256, 0, stream>>>(indeg, bsums, N);
    scan_sums<<<1, 64, 0, stream>>>(bsums, nb1024);
    scan_final<<<nb1024, 256, 0, stream>>>(indeg, bsums, rowptr, cursor, N);
    scatter_kernel<<<gE, 256, 0, stream>>>(esrc, edst, cursor, col, E);

    // 2) conv1
    dim3 ggrid((N + GBM - 1) / GBM, DIMF / GBN);
    gemm_mfma<<<ggrid, 256, 0, stream>>>(x, W1, bufA, N);
    agg_kernel<<<gNode, 256, 0, stream>>>(bufA, rowptr, col, dinv, b1, bufB, N);

    // 3) conv2
    gemm_mfma<<<ggrid, 256, 0, stream>>>(bufB, W2, bufA, N);

    // 4) agg2 + FC + log_softmax fused
    agg_fc_kernel<<<gNode, 256, 0, stream>>>(bufA, rowptr, col, dinv, b2, Wfc, bfc, out, N);
}

// Round 3
// 291.528 us; speedup vs baseline: 2.0827x; 1.4441x over previous
//
#include <hip/hip_runtime.h>
#include <hip/hip_bf16.h>
#include <math.h>

#define DIMF 256   // feature dim (d = h = 256)

typedef __attribute__((ext_vector_type(8))) short s16x8;
typedef __attribute__((ext_vector_type(4))) float f32x4;
typedef __attribute__((ext_vector_type(4))) unsigned short u16x4;
typedef __attribute__((ext_vector_type(8))) unsigned short u16x8;

__device__ __forceinline__ float bf2f(unsigned short u) {
    return __uint_as_float(((unsigned)u) << 16);
}
__device__ __forceinline__ unsigned short f2bf(float f) {  // RNE
    unsigned u = __float_as_uint(f);
    u += 0x7FFFu + ((u >> 16) & 1u);
    return (unsigned short)(u >> 16);
}

// ---------------------------------------------------------------------------
// CSR build
// ---------------------------------------------------------------------------
__global__ __launch_bounds__(256) void hist_kernel(const int* __restrict__ dst,
                                                   int* __restrict__ indeg, int E) {
    int e = blockIdx.x * 256 + threadIdx.x;
    if (e < E) atomicAdd(&indeg[dst[e]], 1);
}

__global__ __launch_bounds__(256) void dinv_kernel(const int* __restrict__ indeg,
                                                   float* __restrict__ dinv, int N) {
    int i = blockIdx.x * 256 + threadIdx.x;
    if (i < N) dinv[i] = rsqrtf((float)(indeg[i] + 1));  // +1 self-loop
}

__global__ __launch_bounds__(256) void scan_partial(const int* __restrict__ indeg,
                                                    int* __restrict__ blockSums, int n) {
    int t = threadIdx.x;
    int base = blockIdx.x * 1024 + t * 4;
    int s = 0;
#pragma unroll
    for (int j = 0; j < 4; ++j) { int i = base + j; if (i < n) s += indeg[i]; }
#pragma unroll
    for (int off = 32; off > 0; off >>= 1) s += __shfl_down(s, off);
    __shared__ int sm[4];
    if ((t & 63) == 0) sm[t >> 6] = s;
    __syncthreads();
    if (t == 0) blockSums[blockIdx.x] = sm[0] + sm[1] + sm[2] + sm[3];
}

__global__ __launch_bounds__(64) void scan_sums(int* __restrict__ blockSums, int nb) {
    int t = threadIdx.x;
    int carry = 0;
    for (int base = 0; base < nb; base += 64) {
        int i = base + t;
        int v = (i < nb) ? blockSums[i] : 0;
        int x = v;
#pragma unroll
        for (int off = 1; off < 64; off <<= 1) {
            int y = __shfl_up(x, off);
            if (t >= off) x += y;
        }
        if (i < nb) blockSums[i] = carry + x - v;  // exclusive
        carry += __shfl(x, 63);
    }
}

__global__ __launch_bounds__(256) void scan_final(const int* __restrict__ indeg,
                                                  const int* __restrict__ blockOffs,
                                                  int* __restrict__ rowptr,
                                                  int* __restrict__ cursor, int n) {
    __shared__ int waveSums[4];
    int t = threadIdx.x;
    int wv = t >> 6, ln = t & 63;
    int base = blockIdx.x * 1024 + t * 4;
    int v[4]; int s = 0;
#pragma unroll
    for (int j = 0; j < 4; ++j) { int i = base + j; v[j] = (i < n) ? indeg[i] : 0; s += v[j]; }
    int x = s;
#pragma unroll
    for (int off = 1; off < 64; off <<= 1) {
        int y = __shfl_up(x, off);
        if (ln >= off) x += y;
    }
    if (ln == 63) waveSums[wv] = x;
    __syncthreads();
    int woff = 0;
    for (int w = 0; w < wv; ++w) woff += waveSums[w];
    int pre = blockOffs[blockIdx.x] + woff + x - s;
#pragma unroll
    for (int j = 0; j < 4; ++j) {
        int i = base + j;
        if (i < n) { rowptr[i] = pre; cursor[i] = pre; }
        pre += v[j];
        if (i == n - 1) rowptr[n] = pre;
    }
}

__global__ __launch_bounds__(256) void scatter_kernel(const int* __restrict__ esrc,
                                                      const int* __restrict__ edst,
                                                      int* __restrict__ cursor,
                                                      int* __restrict__ col, int E) {
    int e = blockIdx.x * 256 + threadIdx.x;
    if (e < E) {
        int d = edst[e];
        int pos = atomicAdd(&cursor[d], 1);
        col[pos] = esrc[e];
    }
}

// ---------------------------------------------------------------------------
// GEMM 1: A fp32 (hi/lo split, fp32-accurate) x B fp32 (hi/lo) -> C bf16
// BM=128, BN=64, BK=32; 256 threads = 4 waves (2x2); wave tile 64x32
// ---------------------------------------------------------------------------
#define GBM 128
#define GBN 64
#define GBK 32
#define APAD 40

__device__ __forceinline__ void split1(float f, unsigned short& h, unsigned short& l) {
    unsigned u = __float_as_uint(f);
    h = (unsigned short)(u >> 16);
    float r = f - __uint_as_float(u & 0xFFFF0000u);
    l = (unsigned short)(__float_as_uint(r) >> 16);
}

__global__ __launch_bounds__(256) void gemm1(const float* __restrict__ A,
                                             const float* __restrict__ B,
                                             unsigned short* __restrict__ C, int M) {
    __shared__ unsigned short Ah[GBM * APAD];
    __shared__ unsigned short Al[GBM * APAD];
    __shared__ unsigned short Bh[GBN * APAD];
    __shared__ unsigned short Bl[GBN * APAD];

    const int t = threadIdx.x;
    const int row0 = blockIdx.x * GBM;
    const int col0 = blockIdx.y * GBN;

    const int sa_r = t >> 1;
    const int sa_kh = (t & 1) * 16;
    const bool sa_valid = (row0 + sa_r) < M;
    const int sb_c = t & 63;
    const int sb_kq = t >> 6;

    const int wv = t >> 6;
    const int wm = wv >> 1;
    const int wn = wv & 1;
    const int ln = t & 63;
    const int lr = ln & 15;
    const int lk = (ln >> 4) * 8;

    f32x4 acc[4][2] = {};

    for (int k0 = 0; k0 < DIMF; k0 += GBK) {
        float4 av[4];
        const float* ap = A + (size_t)(row0 + sa_r) * DIMF + k0 + sa_kh;
#pragma unroll
        for (int i = 0; i < 4; ++i)
            av[i] = sa_valid ? *(const float4*)(ap + 4 * i)
                             : make_float4(0.f, 0.f, 0.f, 0.f);
        float bvv[8];
        const float* bp = B + (size_t)(k0 + sb_kq * 8) * DIMF + col0 + sb_c;
#pragma unroll
        for (int j = 0; j < 8; ++j) bvv[j] = bp[(size_t)j * DIMF];

        __syncthreads();

#pragma unroll
        for (int i = 0; i < 4; ++i) {
            float f[4] = {av[i].x, av[i].y, av[i].z, av[i].w};
            u16x4 h, l;
#pragma unroll
            for (int q = 0; q < 4; ++q) { unsigned short hh, ll; split1(f[q], hh, ll); h[q] = hh; l[q] = ll; }
            *(u16x4*)&Ah[sa_r * APAD + sa_kh + 4 * i] = h;
            *(u16x4*)&Al[sa_r * APAD + sa_kh + 4 * i] = l;
        }
        {
            u16x8 h, l;
#pragma unroll
            for (int j = 0; j < 8; ++j) { unsigned short hh, ll; split1(bvv[j], hh, ll); h[j] = hh; l[j] = ll; }
            *(u16x8*)&Bh[sb_c * APAD + sb_kq * 8] = h;
            *(u16x8*)&Bl[sb_c * APAD + sb_kq * 8] = l;
        }
        __syncthreads();

        s16x8 ah[4], al[4], bh[2], bl[2];
#pragma unroll
        for (int fm = 0; fm < 4; ++fm) {
            int r = wm * 64 + fm * 16 + lr;
            ah[fm] = *(const s16x8*)&Ah[r * APAD + lk];
            al[fm] = *(const s16x8*)&Al[r * APAD + lk];
        }
#pragma unroll
        for (int fn = 0; fn < 2; ++fn) {
            int c = wn * 32 + fn * 16 + lr;
            bh[fn] = *(const s16x8*)&Bh[c * APAD + lk];
            bl[fn] = *(const s16x8*)&Bl[c * APAD + lk];
        }
#pragma unroll
        for (int fm = 0; fm < 4; ++fm)
#pragma unroll
            for (int fn = 0; fn < 2; ++fn) {
                acc[fm][fn] = __builtin_amdgcn_mfma_f32_16x16x32_bf16(ah[fm], bh[fn], acc[fm][fn], 0, 0, 0);
                acc[fm][fn] = __builtin_amdgcn_mfma_f32_16x16x32_bf16(al[fm], bh[fn], acc[fm][fn], 0, 0, 0);
                acc[fm][fn] = __builtin_amdgcn_mfma_f32_16x16x32_bf16(ah[fm], bl[fn], acc[fm][fn], 0, 0, 0);
            }
    }

#pragma unroll
    for (int fm = 0; fm < 4; ++fm)
#pragma unroll
        for (int fn = 0; fn < 2; ++fn)
#pragma unroll
            for (int r = 0; r < 4; ++r) {
                int row = row0 + wm * 64 + fm * 16 + (ln >> 4) * 4 + r;
                int colc = col0 + wn * 32 + fn * 16 + lr;
                if (row < M) C[(size_t)row * DIMF + colc] = f2bf(acc[fm][fn][r]);
            }
}

// ---------------------------------------------------------------------------
// GEMM 2: A bf16 (exact) x B fp32 (hi/lo split) -> C bf16
// ---------------------------------------------------------------------------
__global__ __launch_bounds__(256) void gemm2(const unsigned short* __restrict__ A,
                                             const float* __restrict__ B,
                                             unsigned short* __restrict__ C, int M) {
    __shared__ unsigned short Ah[GBM * APAD];
    __shared__ unsigned short Bh[GBN * APAD];
    __shared__ unsigned short Bl[GBN * APAD];

    const int t = threadIdx.x;
    const int row0 = blockIdx.x * GBM;
    const int col0 = blockIdx.y * GBN;

    const int sa_r = t >> 1;
    const int sa_kh = (t & 1) * 16;
    const bool sa_valid = (row0 + sa_r) < M;
    const int sb_c = t & 63;
    const int sb_kq = t >> 6;

    const int wv = t >> 6;
    const int wm = wv >> 1;
    const int wn = wv & 1;
    const int ln = t & 63;
    const int lr = ln & 15;
    const int lk = (ln >> 4) * 8;

    f32x4 acc[4][2] = {};

    for (int k0 = 0; k0 < DIMF; k0 += GBK) {
        u16x8 a0 = {}, a1 = {};
        if (sa_valid) {
            const unsigned short* ap = A + (size_t)(row0 + sa_r) * DIMF + k0 + sa_kh;
            a0 = *(const u16x8*)ap;
            a1 = *(const u16x8*)(ap + 8);
        }
        float bvv[8];
        const float* bp = B + (size_t)(k0 + sb_kq * 8) * DIMF + col0 + sb_c;
#pragma unroll
        for (int j = 0; j < 8; ++j) bvv[j] = bp[(size_t)j * DIMF];

        __syncthreads();

        *(u16x8*)&Ah[sa_r * APAD + sa_kh] = a0;
        *(u16x8*)&Ah[sa_r * APAD + sa_kh + 8] = a1;
        {
            u16x8 h, l;
#pragma unroll
            for (int j = 0; j < 8; ++j) { unsigned short hh, ll; split1(bvv[j], hh, ll); h[j] = hh; l[j] = ll; }
            *(u16x8*)&Bh[sb_c * APAD + sb_kq * 8] = h;
            *(u16x8*)&Bl[sb_c * APAD + sb_kq * 8] = l;
        }
        __syncthreads();

        s16x8 ah[4], bh[2], bl[2];
#pragma unroll
        for (int fm = 0; fm < 4; ++fm) {
            int r = wm * 64 + fm * 16 + lr;
            ah[fm] = *(const s16x8*)&Ah[r * APAD + lk];
        }
#pragma unroll
        for (int fn = 0; fn < 2; ++fn) {
            int c = wn * 32 + fn * 16 + lr;
            bh[fn] = *(const s16x8*)&Bh[c * APAD + lk];
            bl[fn] = *(const s16x8*)&Bl[c * APAD + lk];
        }
#pragma unroll
        for (int fm = 0; fm < 4; ++fm)
#pragma unroll
            for (int fn = 0; fn < 2; ++fn) {
                acc[fm][fn] = __builtin_amdgcn_mfma_f32_16x16x32_bf16(ah[fm], bh[fn], acc[fm][fn], 0, 0, 0);
                acc[fm][fn] = __builtin_amdgcn_mfma_f32_16x16x32_bf16(ah[fm], bl[fn], acc[fm][fn], 0, 0, 0);
            }
    }

#pragma unroll
    for (int fm = 0; fm < 4; ++fm)
#pragma unroll
        for (int fn = 0; fn < 2; ++fn)
#pragma unroll
            for (int r = 0; r < 4; ++r) {
                int row = row0 + wm * 64 + fm * 16 + (ln >> 4) * 4 + r;
                int colc = col0 + wn * 32 + fn * 16 + lr;
                if (row < M) C[(size_t)row * DIMF + colc] = f2bf(acc[fm][fn][r]);
            }
}

// ---------------------------------------------------------------------------
// Aggregation over bf16 rows: out = relu(di*(di*G[i] + sum dinv[s]*G[s]) + b)
// one wave per node; lane = 4 features (ushort4 = 8B)
// ---------------------------------------------------------------------------
__device__ __forceinline__ void acc4(float4& a, u16x4 h, float w) {
    a.x = fmaf(bf2f(h[0]), w, a.x);
    a.y = fmaf(bf2f(h[1]), w, a.y);
    a.z = fmaf(bf2f(h[2]), w, a.z);
    a.w = fmaf(bf2f(h[3]), w, a.w);
}

__global__ __launch_bounds__(256) void agg_bf16(const unsigned short* __restrict__ G,
                                                const int* __restrict__ rowptr,
                                                const int* __restrict__ col,
                                                const float* __restrict__ dinv,
                                                const float* __restrict__ bias,
                                                unsigned short* __restrict__ out, int N) {
    int wave = threadIdx.x >> 6;
    int lane = threadIdx.x & 63;
    int node = blockIdx.x * 4 + wave;
    if (node >= N) return;

    float di = dinv[node];
    float4 acc = make_float4(0.f, 0.f, 0.f, 0.f);
    {
        u16x4 h = *(const u16x4*)&G[(size_t)node * DIMF + lane * 4];
        acc4(acc, h, di);
    }
    int e0 = rowptr[node], e1 = rowptr[node + 1];
    int e = e0;
    for (; e + 4 <= e1; e += 4) {
        int s0 = col[e + 0], s1 = col[e + 1], s2 = col[e + 2], s3 = col[e + 3];
        float w0 = dinv[s0], w1 = dinv[s1], w2 = dinv[s2], w3 = dinv[s3];
        u16x4 h0 = *(const u16x4*)&G[(size_t)s0 * DIMF + lane * 4];
        u16x4 h1 = *(const u16x4*)&G[(size_t)s1 * DIMF + lane * 4];
        u16x4 h2 = *(const u16x4*)&G[(size_t)s2 * DIMF + lane * 4];
        u16x4 h3 = *(const u16x4*)&G[(size_t)s3 * DIMF + lane * 4];
        acc4(acc, h0, w0); acc4(acc, h1, w1); acc4(acc, h2, w2); acc4(acc, h3, w3);
    }
    for (; e < e1; ++e) {
        int s = col[e];
        u16x4 h = *(const u16x4*)&G[(size_t)s * DIMF + lane * 4];
        acc4(acc, h, dinv[s]);
    }
    float4 b = *(const float4*)&bias[lane * 4];
    u16x4 o;
    o[0] = f2bf(fmaxf(fmaf(acc.x, di, b.x), 0.f));
    o[1] = f2bf(fmaxf(fmaf(acc.y, di, b.y), 0.f));
    o[2] = f2bf(fmaxf(fmaf(acc.z, di, b.z), 0.f));
    o[3] = f2bf(fmaxf(fmaf(acc.w, di, b.w), 0.f));
    *(u16x4*)&out[(size_t)node * DIMF + lane * 4] = o;
}

// ---------------------------------------------------------------------------
// Fused: agg2(bf16) + bias + relu + FC(256->2) + log_softmax -> fp32 out
// ---------------------------------------------------------------------------
__global__ __launch_bounds__(256) void agg_fc_bf16(const unsigned short* __restrict__ G,
                                                   const int* __restrict__ rowptr,
                                                   const int* __restrict__ col,
                                                   const float* __restrict__ dinv,
                                                   const float* __restrict__ bias,
                                                   const float* __restrict__ Wfc,
                                                   const float* __restrict__ bfc,
                                                   float* __restrict__ out, int N) {
    int wave = threadIdx.x >> 6;
    int lane = threadIdx.x & 63;
    int node = blockIdx.x * 4 + wave;
    if (node >= N) return;

    float di = dinv[node];
    float4 acc = make_float4(0.f, 0.f, 0.f, 0.f);
    {
        u16x4 h = *(const u16x4*)&G[(size_t)node * DIMF + lane * 4];
        acc4(acc, h, di);
    }
    int e0 = rowptr[node], e1 = rowptr[node + 1];
    int e = e0;
    for (; e + 4 <= e1; e += 4) {
        int s0 = col[e + 0], s1 = col[e + 1], s2 = col[e + 2], s3 = col[e + 3];
        float w0 = dinv[s0], w1 = dinv[s1], w2 = dinv[s2], w3 = dinv[s3];
        u16x4 h0 = *(const u16x4*)&G[(size_t)s0 * DIMF + lane * 4];
        u16x4 h1 = *(const u16x4*)&G[(size_t)s1 * DIMF + lane * 4];
        u16x4 h2 = *(const u16x4*)&G[(size_t)s2 * DIMF + lane * 4];
        u16x4 h3 = *(const u16x4*)&G[(size_t)s3 * DIMF + lane * 4];
        acc4(acc, h0, w0); acc4(acc, h1, w1); acc4(acc, h2, w2); acc4(acc, h3, w3);
    }
    for (; e < e1; ++e) {
        int s = col[e];
        u16x4 h = *(const u16x4*)&G[(size_t)s * DIMF + lane * 4];
        acc4(acc, h, dinv[s]);
    }
    float4 b = *(const float4*)&bias[lane * 4];
    float h0 = fmaxf(fmaf(acc.x, di, b.x), 0.f);
    float h1 = fmaxf(fmaf(acc.y, di, b.y), 0.f);
    float h2 = fmaxf(fmaf(acc.z, di, b.z), 0.f);
    float h3 = fmaxf(fmaf(acc.w, di, b.w), 0.f);

    float4 w0 = *(const float4*)&Wfc[lane * 8];
    float4 w1 = *(const float4*)&Wfc[lane * 8 + 4];
    float s0 = h0 * w0.x + h1 * w0.z + h2 * w1.x + h3 * w1.z;
    float s1 = h0 * w0.y + h1 * w0.w + h2 * w1.y + h3 * w1.w;
#pragma unroll
    for (int off = 32; off > 0; off >>= 1) {
        s0 += __shfl_xor(s0, off);
        s1 += __shfl_xor(s1, off);
    }
    if (lane == 0) {
        s0 += bfc[0];
        s1 += bfc[1];
        float m = fmaxf(s0, s1);
        float lse = m + logf(__expf(s0 - m) + __expf(s1 - m));
        out[(size_t)node * 2 + 0] = s0 - lse;
        out[(size_t)node * 2 + 1] = s1 - lse;
    }
}

// ---------------------------------------------------------------------------
// Host launcher
// ---------------------------------------------------------------------------
static inline size_t align256(size_t x) { return (x + 255) & ~(size_t)255; }

extern "C" void kernel_launch(void* const* d_in, const int* in_sizes, int n_in,
                              void* d_out, int out_size, void* d_ws, size_t ws_size,
                              hipStream_t stream) {
    const float* x   = (const float*)d_in[0];
    const int* eidx  = (const int*)d_in[1];
    const float* W1  = (const float*)d_in[2];
    const float* b1  = (const float*)d_in[3];
    const float* W2  = (const float*)d_in[4];
    const float* b2  = (const float*)d_in[5];
    const float* Wfc = (const float*)d_in[6];
    const float* bfc = (const float*)d_in[7];
    float* out = (float*)d_out;

    const int N = in_sizes[0] / DIMF;     // 50000
    const int E = in_sizes[1] / 2;        // 800000
    const int* esrc = eidx;
    const int* edst = eidx + E;

    // workspace layout
    char* w = (char*)d_ws;
    size_t off = 0;
    int*   indeg  = (int*)(w + off);   off = align256(off + (size_t)N * 4);
    float* dinv   = (float*)(w + off); off = align256(off + (size_t)N * 4);
    int*   rowptr = (int*)(w + off);   off = align256(off + (size_t)(N + 1) * 4);
    int*   cursor = (int*)(w + off);   off = align256(off + (size_t)N * 4);
    int*   bsums  = (int*)(w + off);   off = align256(off + (size_t)1024 * 4);
    int*   col    = (int*)(w + off);   off = align256(off + (size_t)E * 4);
    unsigned short* bufA = (unsigned short*)(w + off); off = align256(off + (size_t)N * DIMF * 2);
    unsigned short* bufB = (unsigned short*)(w + off); off = align256(off + (size_t)N * DIMF * 2);
    (void)ws_size;

    int gE = (E + 255) / 256;
    int gN = (N + 255) / 256;
    int gNode = (N + 3) / 4;
    int nb1024 = (N + 1023) / 1024;

    // 1) CSR build
    hipMemsetAsync(indeg, 0, (size_t)N * 4, stream);
    hist_kernel<<<gE, 256, 0, stream>>>(edst, indeg, E);
    dinv_kernel<<<gN, 256, 0, stream>>>(indeg, dinv, N);
    scan_partial<<<nb1024, 256, 0, stream>>>(indeg, bsums, N);
    scan_sums<<<1, 64, 0, stream>>>(bsums, nb1024);
    scan_final<<<nb1024, 256, 0, stream>>>(indeg, bsums, rowptr, cursor, N);
    scatter_kernel<<<gE, 256, 0, stream>>>(esrc, edst, cursor, col, E);

    // 2) conv1: bufA = bf16(x @ W1); bufB = bf16(relu(agg(bufA) + b1))
    dim3 ggrid((N + GBM - 1) / GBM, DIMF / GBN);
    gemm1<<<ggrid, 256, 0, stream>>>(x, W1, bufA, N);
    agg_bf16<<<gNode, 256, 0, stream>>>(bufA, rowptr, col, dinv, b1, bufB, N);

    // 3) conv2: bufA = bf16(bufB @ W2)
    gemm2<<<ggrid, 256, 0, stream>>>(bufB, W2, bufA, N);

    // 4) agg2 + FC + log_softmax fused
    agg_fc_bf16<<<gNode, 256, 0, stream>>>(bufA, rowptr, col, dinv, b2, Wfc, bfc, out, N);
}